// Round 13
// baseline (323.465 us; speedup 1.0000x reference)
//
#include <hip/hip_runtime.h>

#define BATCH 16
#define TXT   320
#define NMELC 80
#define MELT  2000
#define DIAGS 2240   // rows of skewed lpS (max written 2158; dp reads < 2214)
#define PADM  1.0e12f
#define EPSC  1e-7f
#define L2E   1.4426950408889634f
#define LN2   0.6931471805599453f
#define EPSL2 1.4426950e-7f
#define KZERO (-1073741824)

// ---------------------------------------------------------------------------
// Kernel A: log_prob[b,j,t] = s*(xx - 2xm + mm),  s = -0.5/80  (unchanged)
// ---------------------------------------------------------------------------
__global__ __launch_bounds__(256) void lp_kernel(
    const float* __restrict__ mlv,   // (B,320,160)
    const float* __restrict__ ms,    // (B,80,2000)
    float* __restrict__ out_lp)      // (B,320,2000)  (d_out+1)
{
    __shared__ float Gt[16][64];
    __shared__ float Ft[16][256];
    __shared__ float bias_s[64];
    __shared__ float bias_p[256];

    const int b   = blockIdx.z;
    const int j0  = blockIdx.y * 64;
    const int t0  = blockIdx.x * 256;
    const int tid = threadIdx.x;
    const float s = -0.00625f;  // -0.5/80

    const float* mlv_b = mlv + (size_t)b * TXT * 160;
    const float* ms_b  = ms  + (size_t)b * NMELC * MELT;

    {
        const int jj = tid >> 2;
        const int q  = tid & 3;
        const float* p = mlv_b + (size_t)(j0 + jj) * 160 + q * 20;
        float part = 0.f;
        #pragma unroll
        for (int c = 0; c < 20; ++c) {
            float mu = p[c];
            float lv = p[c + 80];
            float iv = __expf(-lv);
            part += mu * mu * iv + lv;
        }
        bias_p[tid] = part;
    }
    __syncthreads();
    if (tid < 64) {
        float v = bias_p[tid * 4] + bias_p[tid * 4 + 1] +
                  bias_p[tid * 4 + 2] + bias_p[tid * 4 + 3];
        bias_s[tid] = s * v;
    }

    float acc[8][8];
    #pragma unroll
    for (int i = 0; i < 8; ++i)
        #pragma unroll
        for (int k = 0; k < 8; ++k) acc[i][k] = 0.f;

    const int jg = tid >> 5;   // 0..7
    const int tg = tid & 31;   // 0..31

    for (int kc = 0; kc < 10; ++kc) {
        const int c0 = kc * 8;
        __syncthreads();
        #pragma unroll
        for (int i = 0; i < 2; ++i) {
            int f   = tid + i * 256;
            int cr  = f >> 6;
            int col = f & 63;
            float mu = mlv_b[(size_t)(j0 + col) * 160 + (c0 + cr)];
            float lv = mlv_b[(size_t)(j0 + col) * 160 + (80 + c0 + cr)];
            float iv = __expf(-lv);
            Gt[cr][col]     = s * iv;
            Gt[cr + 8][col] = -2.f * s * mu * iv;
        }
        #pragma unroll
        for (int i = 0; i < 2; ++i) {
            int f   = tid + i * 256;
            int row = f >> 6;
            int c4  = f & 63;
            int t   = t0 + c4 * 4;
            float4 v = (t + 3 < MELT)
                ? *(const float4*)&ms_b[(size_t)(c0 + row) * MELT + t]
                : make_float4(0.f, 0.f, 0.f, 0.f);
            *(float4*)&Ft[row][c4 * 4] =
                make_float4(v.x * v.x, v.y * v.y, v.z * v.z, v.w * v.w);
            *(float4*)&Ft[row + 8][c4 * 4] = v;
        }
        __syncthreads();
        #pragma unroll
        for (int k = 0; k < 16; ++k) {
            float4 g0 = *(const float4*)&Gt[k][jg * 8];
            float4 g1 = *(const float4*)&Gt[k][jg * 8 + 4];
            float4 f0 = *(const float4*)&Ft[k][tg * 8];
            float4 f1 = *(const float4*)&Ft[k][tg * 8 + 4];
            float ga[8] = {g0.x, g0.y, g0.z, g0.w, g1.x, g1.y, g1.z, g1.w};
            float fa[8] = {f0.x, f0.y, f0.z, f0.w, f1.x, f1.y, f1.z, f1.w};
            #pragma unroll
            for (int ji = 0; ji < 8; ++ji)
                #pragma unroll
                for (int ti = 0; ti < 8; ++ti)
                    acc[ji][ti] = fmaf(ga[ji], fa[ti], acc[ji][ti]);
        }
    }

    #pragma unroll
    for (int ji = 0; ji < 8; ++ji) {
        int j = j0 + jg * 8 + ji;
        float bs = bias_s[jg * 8 + ji];
        float* orow = out_lp + (size_t)(b * TXT + j) * MELT;
        #pragma unroll
        for (int ti = 0; ti < 8; ++ti) {
            int t = t0 + tg * 8 + ti;
            if (t < MELT) orow[t] = acc[ji][ti] + bs;
        }
    }
}

// ---------------------------------------------------------------------------
// Kernel A2: LDS-transpose into pair-skewed layout, LINEAR domain.
// lpS[b][t + (j>>1)][j] = exp2(max(lp*L2E + EPS*L2E, -120))   (p > 0, normal)
// ---------------------------------------------------------------------------
__global__ __launch_bounds__(256) void tr_kernel(
    const float* __restrict__ lp,    // (B,320,2000)
    float* __restrict__ lpS)         // (B,DIAGS,320)
{
    __shared__ float T[64][65];
    const int b    = blockIdx.z;
    const int j0   = blockIdx.y * 64;
    const int t0   = blockIdx.x * 64;
    const int tid  = threadIdx.x;
    const int lane = tid & 63;
    const int qg   = tid >> 6;       // 0..3

    #pragma unroll 4
    for (int it = 0; it < 16; ++it) {
        int j = j0 + qg * 16 + it;
        int t = t0 + lane;
        float v = (t < MELT) ? lp[((size_t)b * TXT + j) * MELT + t] : 0.f;
        float P = fmaxf(fmaf(v, L2E, EPSL2), -120.0f);
        T[qg * 16 + it][lane] = exp2f(P);
    }
    __syncthreads();

    const int rbase = t0 + (j0 >> 1);
    float* orow = lpS + ((size_t)b * DIAGS + rbase) * TXT + j0 + lane;
    #pragma unroll 4
    for (int k = 0; k < 24; ++k) {
        int d = qg + 4 * k;          // r - rbase
        if (d > 94) break;
        int tloc = d - (lane >> 1);
        if (tloc >= 0 && tloc < 64 && (t0 + tloc) < MELT)
            orow[(size_t)d * TXT] = T[lane][tloc];
    }
}

// ---------------------------------------------------------------------------
// Kernel B: forward DP v12 — scaled-linear (m,k), LIBCALL-FREE chain.
// All full-rate VALU: smax / isub / v_lshl_add (scale = bitcast((d+127)<<23),
// d clamped at -126 so s <= 1, no overflow) / fma / fmul / bfe / iadd.
// 2 j/lane, systolic skew i=t+l, DPP wave_shr:1 neighbor, pair-skew coalesced
// float2 loads of linear p. Structure identical to r12 (verified correct).
// ---------------------------------------------------------------------------
__device__ __forceinline__ float dpp_shr1(float x) {
    return __int_as_float(__builtin_amdgcn_update_dpp(
        0, __float_as_int(x), 0x138 /*wave_shr:1*/, 0xF, 0xF, false));
}
__device__ __forceinline__ int dpp_shr1_i(int x) {
    return __builtin_amdgcn_update_dpp(0, x, 0x138, 0xF, 0xF, false);
}

__global__ __launch_bounds__(192, 1) void dp_kernel(
    const float* __restrict__ lpS,   // (B,DIAGS,320) linear p
    const float* __restrict__ lp,    // out_lp (for lp[b,0,0])
    const int* __restrict__ tlen,
    const int* __restrict__ mlen,
    float* __restrict__ res,
    float* __restrict__ out0)
{
    __shared__ float bnd_m[2][2056];
    __shared__ int   bnd_k[2][2056];
    __shared__ int   prog[2];

    const int b    = blockIdx.x;
    const int tid  = threadIdx.x;
    const int w    = tid >> 6;
    const int l    = tid & 63;
    const int tend = mlen[b] - 1;
    const int tl   = tlen[b];

    if (tid < 2) prog[tid] = 0;

    const float* rowp = lpS + (size_t)b * DIAGS * TXT
                      + (size_t)(64 * w) * TXT + 2 * tid;

    // init: alpha_0[0] = lp00 (log2 dom) -> (m in [1,2), k); others zero-state
    float M1 = 0.f, M2 = 0.f;
    int   K1 = KZERO, K2 = KZERO;
    if (tid == 0) {
        float x = lp[(size_t)b * TXT * MELT] * L2E;
        int k0 = (int)floorf(x);
        M1 = exp2f(x - (float)k0);   // [1,2)
        K1 = k0;
    }
    float M1F = M1, M2F = M2; int K1F = K1, K2F = K2;

    if (l == 63 && w < 2) { bnd_m[w][0] = 0.f; bnd_k[w][0] = KZERO; }
    __syncthreads();

    if (w == 2 && tl < 257) return;   // wave 2 unused

    float ptAm = 0.f, ptBm = 0.f;
    int   ptAk = KZERO, ptBk = KZERO;
    const bool is0     = (l == 0);
    const bool isPub   = (l == 63) && (w < 2);
    const bool hasRing = (w > 0);
    int seen = 0;

    const int imax = tend + 63;

    float PA[16], PB[16], PC[16];
    #pragma unroll
    for (int q = 0; q < 8; ++q) {
        float2 v = *(const float2*)&rowp[(size_t)(1 + q) * TXT];
        PA[2 * q] = v.x; PA[2 * q + 1] = v.y;
    }
    #pragma unroll
    for (int q = 0; q < 8; ++q) {
        float2 v = *(const float2*)&rowp[(size_t)(9 + q) * TXT];
        PB[2 * q] = v.x; PB[2 * q + 1] = v.y;
    }
    const float* pref = rowp + (size_t)17 * TXT;

#define RING_RD(BM_, BK_, T0_)                                               \
    {                                                                        \
        float4 r0_ = *(const float4*)&bnd_m[w - 1][T0_];                     \
        float4 r1_ = *(const float4*)&bnd_m[w - 1][(T0_) + 4];               \
        int4   s0_ = *(const int4*)&bnd_k[w - 1][T0_];                       \
        int4   s1_ = *(const int4*)&bnd_k[w - 1][(T0_) + 4];                 \
        BM_[0]=r0_.x; BM_[1]=r0_.y; BM_[2]=r0_.z; BM_[3]=r0_.w;              \
        BM_[4]=r1_.x; BM_[5]=r1_.y; BM_[6]=r1_.z; BM_[7]=r1_.w;              \
        BK_[0]=s0_.x; BK_[1]=s0_.y; BK_[2]=s0_.z; BK_[3]=s0_.w;              \
        BK_[4]=s1_.x; BK_[5]=s1_.y; BK_[6]=s1_.z; BK_[7]=s1_.w;              \
    }
#define RING_POLL(NEED_)                                                     \
    if (seen < (NEED_)) {                                                    \
        int tgt_ = (NEED_) + 32;                                             \
        if (tgt_ > tend - 1) tgt_ = tend - 1;                                \
        if (tgt_ < (NEED_)) tgt_ = (NEED_);                                  \
        volatile int* pv_ = &prog[w - 1];                                    \
        int v_ = *pv_;                                                       \
        while (v_ < tgt_) { __builtin_amdgcn_s_sleep(1); v_ = *pv_; }        \
        seen = v_;                                                           \
        __asm__ volatile("" ::: "memory");                                   \
    }

    float bqCm[8]; int bqCk[8];
    if (hasRing) {
        RING_POLL(7)
        RING_RD(bqCm, bqCk, 0)
    } else {
        #pragma unroll
        for (int q = 0; q < 8; ++q) { bqCm[q] = 0.f; bqCk[q] = KZERO; }
    }

// one iteration = 2 DP j-steps; all full-rate VALU, no libcalls
#define STEP2(Pc_, q_, MQ_, KQ_)                                             \
    {                                                                        \
        float nm_ = is0 ? bqCm[q_] : ptAm;                                   \
        int   nk_ = is0 ? bqCk[q_] : ptAk;                                   \
        int Ke_ = (K1 > nk_) ? K1 : nk_;                                     \
        int d1_ = K1 - Ke_;  d1_ = (d1_ < -126) ? -126 : d1_;                \
        int dn_ = nk_ - Ke_; dn_ = (dn_ < -126) ? -126 : dn_;                \
        float s1_ = __int_as_float((d1_ + 127) << 23);                       \
        float sn_ = __int_as_float((dn_ + 127) << 23);                       \
        float te_ = fmaf(M1, s1_, nm_ * sn_) * Pc_[2 * q_];                  \
        unsigned ue_ = __float_as_uint(te_);                                 \
        float M1n_ = __uint_as_float((ue_ & 0x807FFFFFu) | 0x3F800000u);     \
        int   K1n_ = Ke_ + (int)((ue_ >> 23) & 0xFFu) - 127;                 \
        int Ko_ = (K2 > K1) ? K2 : K1;                                       \
        int d2_ = K2 - Ko_; d2_ = (d2_ < -126) ? -126 : d2_;                 \
        int dq_ = K1 - Ko_; dq_ = (dq_ < -126) ? -126 : dq_;                 \
        float s2_ = __int_as_float((d2_ + 127) << 23);                       \
        float sq_ = __int_as_float((dq_ + 127) << 23);                       \
        float to_ = fmaf(M2, s2_, M1 * sq_) * Pc_[2 * q_ + 1];               \
        unsigned uo_ = __float_as_uint(to_);                                 \
        float M2n_ = __uint_as_float((uo_ & 0x807FFFFFu) | 0x3F800000u);     \
        int   K2n_ = Ko_ + (int)((uo_ >> 23) & 0xFFu) - 127;                 \
        float nsm_ = dpp_shr1(M2n_);                                         \
        int   nsk_ = dpp_shr1_i(K2n_);                                       \
        ptAm = ptBm; ptBm = nsm_;                                            \
        ptAk = ptBk; ptBk = nsk_;                                            \
        M1 = M1n_; K1 = K1n_; M2 = M2n_; K2 = K2n_;                          \
        MQ_ = M2n_; KQ_ = K2n_;                                              \
    }

#define GROUP2_S(Pc_, Pl_, I0_)                                              \
{                                                                            \
    float bqNm[8]; int bqNk[8];                                              \
    if (hasRing) {                                                           \
        const int nt0_ = (I0_) + 7;                                          \
        RING_POLL(nt0_ + 7)                                                  \
        RING_RD(bqNm, bqNk, nt0_)                                            \
    } else {                                                                 \
        _Pragma("unroll") for (int q_=0;q_<8;++q_)                           \
            { bqNm[q_] = 0.f; bqNk[q_] = KZERO; }                            \
    }                                                                        \
    _Pragma("unroll") for (int q_=0;q_<8;++q_) {                             \
        float2 v_ = *(const float2*)&pref[(size_t)q_ * TXT];                 \
        Pl_[2*q_] = v_.x; Pl_[2*q_+1] = v_.y;                                \
    }                                                                        \
    float mq[8]; int kq[8];                                                  \
    _Pragma("unroll")                                                        \
    for (int q_=0;q_<8;++q_) STEP2(Pc_, q_, mq[q_], kq[q_])                  \
    if (isPub) {                                                             \
        const int t63_ = (I0_) - 63;                                         \
        if (t63_ >= 1) {                                                     \
            _Pragma("unroll") for (int q_=0;q_<8;++q_) {                     \
                bnd_m[w][t63_ + q_] = mq[q_];                                \
                bnd_k[w][t63_ + q_] = kq[q_];                                \
            }                                                                \
        } else {                                                             \
            _Pragma("unroll") for (int q_=0;q_<8;++q_)                       \
                if (t63_ + q_ >= 1) {                                        \
                    bnd_m[w][t63_ + q_] = mq[q_];                            \
                    bnd_k[w][t63_ + q_] = kq[q_];                            \
                }                                                            \
        }                                                                    \
        __asm__ volatile("" ::: "memory");  /* DS pipe is in-order */        \
        int pgv_ = t63_ + 7;                                                 \
        if (pgv_ >= 1) prog[w] = pgv_;                                       \
    }                                                                        \
    pref += (size_t)8 * TXT;                                                 \
    _Pragma("unroll") for (int q_=0;q_<8;++q_)                               \
        { bqCm[q_] = bqNm[q_]; bqCk[q_] = bqNk[q_]; }                        \
}

#define GROUP2_T(Pc_, Pl_, I0_)                                              \
{                                                                            \
    float bqNm[8]; int bqNk[8];                                              \
    if (hasRing) {                                                           \
        const int nt0_ = (I0_) + 7;                                          \
        int need_ = nt0_ + 7; if (need_ > tend - 1) need_ = tend - 1;        \
        RING_POLL(need_)                                                     \
        const int rb_ = nt0_ > 2048 ? 2048 : nt0_;                           \
        RING_RD(bqNm, bqNk, rb_)                                             \
    } else {                                                                 \
        _Pragma("unroll") for (int q_=0;q_<8;++q_)                           \
            { bqNm[q_] = 0.f; bqNk[q_] = KZERO; }                            \
    }                                                                        \
    _Pragma("unroll") for (int q_=0;q_<8;++q_) {                             \
        float2 v_ = *(const float2*)&pref[(size_t)q_ * TXT];                 \
        Pl_[2*q_] = v_.x; Pl_[2*q_+1] = v_.y;                                \
    }                                                                        \
    float mq[8]; int kq[8];                                                  \
    const int vt_ = (I0_) - l;                                               \
    _Pragma("unroll")                                                        \
    for (int q_=0;q_<8;++q_) {                                               \
        STEP2(Pc_, q_, mq[q_], kq[q_])                                       \
        bool c_ = (vt_ + q_ == tend);                                        \
        M1F = c_ ? M1 : M1F;  K1F = c_ ? K1 : K1F;                           \
        M2F = c_ ? M2 : M2F;  K2F = c_ ? K2 : K2F;                           \
    }                                                                        \
    if (isPub) {                                                             \
        const int t63_ = (I0_) - 63;                                         \
        _Pragma("unroll") for (int q_=0;q_<8;++q_) {                         \
            int tq_ = t63_ + q_;                                             \
            if (tq_ >= 1 && tq_ <= tend) {                                   \
                bnd_m[w][tq_] = mq[q_];                                      \
                bnd_k[w][tq_] = kq[q_];                                      \
            }                                                                \
        }                                                                    \
        __asm__ volatile("" ::: "memory");                                   \
        int pgv_ = t63_ + 7; if (pgv_ > tend) pgv_ = tend;                   \
        if (pgv_ >= 1) prog[w] = pgv_;                                       \
    }                                                                        \
    pref += (size_t)8 * TXT;                                                 \
    _Pragma("unroll") for (int q_=0;q_<8;++q_)                               \
        { bqCm[q_] = bqNm[q_]; bqCk[q_] = bqNk[q_]; }                        \
}

    int i0 = 1;
    const int sEnd = tend - 23;   // steady: latch can't fire
    int ph = 0;
    while (i0 <= sEnd) {
        GROUP2_S(PA, PC, i0); i0 += 8;
        if (i0 > sEnd) { ph = 1; break; }
        GROUP2_S(PB, PA, i0); i0 += 8;
        if (i0 > sEnd) { ph = 2; break; }
        GROUP2_S(PC, PB, i0); i0 += 8;
    }
    if (ph == 1) {
        #pragma unroll
        for (int q = 0; q < 16; ++q) {
            float tmp = PA[q]; PA[q] = PB[q]; PB[q] = PC[q]; PC[q] = tmp;
        }
    } else if (ph == 2) {
        #pragma unroll
        for (int q = 0; q < 16; ++q) {
            float tmp = PA[q]; PA[q] = PC[q]; PC[q] = PB[q]; PB[q] = tmp;
        }
    }
    while (i0 <= imax) {
        GROUP2_T(PA, PC, i0); i0 += 8;
        if (i0 > imax) break;
        GROUP2_T(PB, PA, i0); i0 += 8;
        if (i0 > imax) break;
        GROUP2_T(PC, PB, i0); i0 += 8;
    }

#undef GROUP2_S
#undef GROUP2_T
#undef STEP2
#undef RING_RD
#undef RING_POLL

    if (tid == ((tl - 1) >> 1)) {
        float mf; int kf;
        if ((tl - 1) & 1) { mf = M2F; kf = K2F; }
        else              { mf = M1F; kf = K1F; }
        float v = ((float)kf + log2f(mf)) * LN2 / (float)(tend + 1);
        if (res) res[b] = v;
        else     atomicAdd(out0, -v / (float)BATCH);
    }
}

// ---------------------------------------------------------------------------
// Fallback DP (r9 log-domain, reads out_lp directly) for small ws.
// ---------------------------------------------------------------------------
__global__ __launch_bounds__(192, 1) void dp_kernel_fb(
    const float* __restrict__ lp,
    const int* __restrict__ tlen,
    const int* __restrict__ mlen,
    float* __restrict__ res,
    float* __restrict__ out0)
{
    __shared__ float bnd[2][2056];
    __shared__ int   prog[2];

    const int b    = blockIdx.x;
    const int tid  = threadIdx.x;
    const int w    = tid >> 6;
    const int l    = tid & 63;
    const int tend = mlen[b] - 1;
    const int tl   = tlen[b];

    if (tid < 2) prog[tid] = 0;

    int j0c = 2 * tid; if (j0c > 318) j0c = 318;
    const float* r0 = lp + (size_t)(b * TXT + j0c) * MELT;
    const float* r1 = r0 + MELT;

    float A1 = (tid == 0) ? lp[(size_t)b * TXT * MELT] * L2E : -PADM;
    float A2 = -PADM;
    float A1F = A1, A2F = A2;

    if (l == 63 && w < 2) bnd[w][0] = -PADM;
    __syncthreads();

    if (w == 2 && tl < 257) return;

    float ptA2 = -PADM, ptB2 = -PADM;
    const bool is0     = (l == 0);
    const bool isPub   = (l == 63) && (w < 2);
    const bool hasRing = (w > 0);
    int seen = 0;

    const int imax = tend + 63;

    float PA[16], PB[16], PC[16];
    #pragma unroll
    for (int q = 0; q < 8; ++q) { PA[2*q] = r0[1 + q - l]; PA[2*q+1] = r1[1 + q - l]; }
    #pragma unroll
    for (int q = 0; q < 8; ++q) { PB[2*q] = r0[9 + q - l]; PB[2*q+1] = r1[9 + q - l]; }
    #pragma unroll
    for (int q = 0; q < 16; ++q) PA[q] = fmaf(PA[q], L2E, EPSL2);

    const float* p0 = r0 + 17 - l;
    const float* p1 = r1 + 17 - l;

#define RING_RD(BQ_, T0_)                                                    \
    {                                                                        \
        float4 q0_ = *(const float4*)&bnd[w - 1][T0_];                       \
        float4 q1_ = *(const float4*)&bnd[w - 1][(T0_) + 4];                 \
        BQ_[0]=q0_.x; BQ_[1]=q0_.y; BQ_[2]=q0_.z; BQ_[3]=q0_.w;              \
        BQ_[4]=q1_.x; BQ_[5]=q1_.y; BQ_[6]=q1_.z; BQ_[7]=q1_.w;              \
    }
#define RING_POLL(NEED_)                                                     \
    if (seen < (NEED_)) {                                                    \
        int tgt_ = (NEED_) + 32;                                             \
        if (tgt_ > tend - 1) tgt_ = tend - 1;                                \
        if (tgt_ < (NEED_)) tgt_ = (NEED_);                                  \
        volatile int* pv_ = &prog[w - 1];                                    \
        int v_ = *pv_;                                                       \
        while (v_ < tgt_) { __builtin_amdgcn_s_sleep(1); v_ = *pv_; }        \
        seen = v_;                                                           \
        __asm__ volatile("" ::: "memory");                                   \
    }

    float bqC[8];
    if (hasRing) {
        RING_POLL(7)
        RING_RD(bqC, 0)
    } else {
        #pragma unroll
        for (int q = 0; q < 8; ++q) bqC[q] = -PADM;
    }

#define STEP2(Pc_, q_, AQ_)                                                  \
    {                                                                        \
        float pt_ = is0 ? bqC[q_] : ptA2;                                    \
        float m1_ = fmaxf(A1, pt_);                                          \
        float d1_ = A1 - pt_;                                                \
        float e1_ = __builtin_amdgcn_exp2f(-fabsf(d1_));                     \
        float g1_ = __builtin_amdgcn_logf(1.0f + e1_);                       \
        float n1_ = m1_ + g1_ + Pc_[2 * q_];                                 \
        float m2_ = fmaxf(A2, A1);                                           \
        float d2_ = A2 - A1;                                                 \
        float e2_ = __builtin_amdgcn_exp2f(-fabsf(d2_));                     \
        float g2_ = __builtin_amdgcn_logf(1.0f + e2_);                       \
        float n2_ = m2_ + g2_ + Pc_[2 * q_ + 1];                             \
        float ns_ = __int_as_float(__builtin_amdgcn_update_dpp(              \
            0, __float_as_int(n2_), 0x138, 0xF, 0xF, false));                \
        ptA2 = ptB2; ptB2 = ns_;                                             \
        A1 = n1_; A2 = n2_; AQ_ = n2_;                                       \
    }

#define GROUP2_S(Pc_, Pm_, Pl_, I0_)                                         \
{                                                                            \
    float bqN[8];                                                            \
    if (hasRing) {                                                           \
        const int nt0_ = (I0_) + 7;                                          \
        RING_POLL(nt0_ + 7)                                                  \
        RING_RD(bqN, nt0_)                                                   \
    } else {                                                                 \
        _Pragma("unroll") for (int q_=0;q_<8;++q_) bqN[q_] = -PADM;          \
    }                                                                        \
    _Pragma("unroll") for (int q_=0;q_<8;++q_) {                             \
        Pl_[2*q_] = p0[q_]; Pl_[2*q_+1] = p1[q_];                            \
    }                                                                        \
    float aq2[8];                                                            \
    _Pragma("unroll")                                                        \
    for (int q_=0;q_<8;++q_) STEP2(Pc_, q_, aq2[q_])                         \
    if (isPub) {                                                             \
        const int t63_ = (I0_) - 63;                                         \
        if (t63_ >= 1) {                                                     \
            _Pragma("unroll") for (int q_=0;q_<8;++q_)                       \
                bnd[w][t63_ + q_] = aq2[q_];                                 \
        } else {                                                             \
            _Pragma("unroll") for (int q_=0;q_<8;++q_)                       \
                if (t63_ + q_ >= 1) bnd[w][t63_ + q_] = aq2[q_];             \
        }                                                                    \
        __asm__ volatile("" ::: "memory");                                   \
        int pgv_ = t63_ + 7;                                                 \
        if (pgv_ >= 1) prog[w] = pgv_;                                       \
    }                                                                        \
    p0 += 8; p1 += 8;                                                        \
    _Pragma("unroll") for (int q_=0;q_<16;++q_)                              \
        Pm_[q_] = fmaf(Pm_[q_], L2E, EPSL2);                                 \
    _Pragma("unroll") for (int q_=0;q_<8;++q_) bqC[q_] = bqN[q_];            \
}

#define GROUP2_T(Pc_, Pm_, Pl_, I0_)                                         \
{                                                                            \
    float bqN[8];                                                            \
    if (hasRing) {                                                           \
        const int nt0_ = (I0_) + 7;                                          \
        int need_ = nt0_ + 7; if (need_ > tend - 1) need_ = tend - 1;        \
        RING_POLL(need_)                                                     \
        const int rb_ = nt0_ > 2048 ? 2048 : nt0_;                           \
        RING_RD(bqN, rb_)                                                    \
    } else {                                                                 \
        _Pragma("unroll") for (int q_=0;q_<8;++q_) bqN[q_] = -PADM;          \
    }                                                                        \
    _Pragma("unroll") for (int q_=0;q_<8;++q_) {                             \
        int t_ = (I0_) + 16 + q_ - l;                                        \
        t_ = t_ < 0 ? 0 : (t_ > tend ? tend : t_);                           \
        Pl_[2*q_] = r0[t_]; Pl_[2*q_+1] = r1[t_];                            \
    }                                                                        \
    float aq2[8];                                                            \
    const int vt_ = (I0_) - l;                                               \
    _Pragma("unroll")                                                        \
    for (int q_=0;q_<8;++q_) {                                               \
        STEP2(Pc_, q_, aq2[q_])                                              \
        bool c_ = (vt_ + q_ == tend);                                        \
        A1F = c_ ? A1 : A1F;                                                 \
        A2F = c_ ? A2 : A2F;                                                 \
    }                                                                        \
    if (isPub) {                                                             \
        const int t63_ = (I0_) - 63;                                         \
        _Pragma("unroll") for (int q_=0;q_<8;++q_) {                         \
            int tq_ = t63_ + q_;                                             \
            if (tq_ >= 1 && tq_ <= tend) bnd[w][tq_] = aq2[q_];              \
        }                                                                    \
        __asm__ volatile("" ::: "memory");                                   \
        int pgv_ = t63_ + 7; if (pgv_ > tend) pgv_ = tend;                   \
        if (pgv_ >= 1) prog[w] = pgv_;                                       \
    }                                                                        \
    _Pragma("unroll") for (int q_=0;q_<16;++q_)                              \
        Pm_[q_] = fmaf(Pm_[q_], L2E, EPSL2);                                 \
    _Pragma("unroll") for (int q_=0;q_<8;++q_) bqC[q_] = bqN[q_];            \
}

    int i0 = 1;
    const int sEnd = tend - 23;
    int ph = 0;
    while (i0 <= sEnd) {
        GROUP2_S(PA, PB, PC, i0); i0 += 8;
        if (i0 > sEnd) { ph = 1; break; }
        GROUP2_S(PB, PC, PA, i0); i0 += 8;
        if (i0 > sEnd) { ph = 2; break; }
        GROUP2_S(PC, PA, PB, i0); i0 += 8;
    }
    if (ph == 1) {
        #pragma unroll
        for (int q = 0; q < 16; ++q) {
            float tmp = PA[q]; PA[q] = PB[q]; PB[q] = PC[q]; PC[q] = tmp;
        }
    } else if (ph == 2) {
        #pragma unroll
        for (int q = 0; q < 16; ++q) {
            float tmp = PA[q]; PA[q] = PC[q]; PC[q] = PB[q]; PB[q] = tmp;
        }
    }
    while (i0 <= imax) {
        GROUP2_T(PA, PB, PC, i0); i0 += 8;
        if (i0 > imax) break;
        GROUP2_T(PB, PC, PA, i0); i0 += 8;
        if (i0 > imax) break;
        GROUP2_T(PC, PA, PB, i0); i0 += 8;
    }

#undef GROUP2_S
#undef GROUP2_T
#undef STEP2
#undef RING_RD
#undef RING_POLL

    if (tid == ((tl - 1) >> 1)) {
        float Af = ((tl - 1) & 1) ? A2F : A1F;
        float v = Af * LN2 / (float)(tend + 1);
        if (res) res[b] = v;
        else     atomicAdd(out0, -v / (float)BATCH);
    }
}

__global__ void zero1_kernel(float* out0) { out0[0] = 0.f; }

__global__ void fin_kernel(const float* __restrict__ res, float* __restrict__ out0)
{
    int l = threadIdx.x;
    float v = (l < BATCH) ? res[l] : 0.f;
    #pragma unroll
    for (int off = 32; off; off >>= 1) v += __shfl_down(v, off);
    if (l == 0) out0[0] = -(v / (float)BATCH);
}

// ---------------------------------------------------------------------------
extern "C" void kernel_launch(void* const* d_in, const int* in_sizes, int n_in,
                              void* d_out, int out_size, void* d_ws, size_t ws_size,
                              hipStream_t stream)
{
    const float* mlv = (const float*)d_in[0];
    const float* ms  = (const float*)d_in[1];
    const int*   tl  = (const int*)d_in[2];
    const int*   ml  = (const int*)d_in[3];
    float* out    = (float*)d_out;
    float* out_lp = out + 1;

    const size_t lpS_bytes = (size_t)BATCH * DIAGS * TXT * sizeof(float);
    bool res_ok = ws_size >= 128;
    bool has_S  = ws_size >= 128 + lpS_bytes;
    float* res = res_ok ? (float*)d_ws : nullptr;
    float* lpS = has_S ? (float*)((char*)d_ws + 128) : nullptr;

    dim3 gA(8, 5, 16);   // t-tiles(256), j-tiles(64), batch
    lp_kernel<<<gA, 256, 0, stream>>>(mlv, ms, out_lp);

    if (!res_ok) zero1_kernel<<<1, 1, 0, stream>>>(out);
    if (has_S) {
        tr_kernel<<<dim3(32, 5, 16), 256, 0, stream>>>(out_lp, lpS);
        dp_kernel<<<BATCH, 192, 0, stream>>>(lpS, out_lp, tl, ml, res, out);
    } else {
        dp_kernel_fb<<<BATCH, 192, 0, stream>>>(out_lp, tl, ml, res, out);
    }
    if (res_ok) fin_kernel<<<1, 64, 0, stream>>>(res, out);
}

// Round 14
// 243.719 us; speedup vs baseline: 1.3272x; 1.3272x over previous
//
#include <hip/hip_runtime.h>

#define BATCH 16
#define TXT   320
#define NMELC 80
#define MELT  2000
#define PADM  1.0e12f
#define L2E   1.4426950408889634f
#define LN2   0.6931471805599453f
#define EPSL2 1.4426950e-7f

// ---------------------------------------------------------------------------
// lp block body: log_prob[b,j,t] = s*(xx - 2xm + mm), s=-0.5/80.
// 64j x 256t tile, 256 threads, 8j x 8t per thread. (verified r5..r13)
// SM layout: Gt[16][64] @0, Ft[16][256] @1024, bias_p @5120, bias_s @5376.
// ---------------------------------------------------------------------------
__device__ __forceinline__ void lp_block(
    const float* __restrict__ mlv, const float* __restrict__ ms,
    float* __restrict__ out_lp, int b, int j0, int t0, float* SM)
{
    float (*Gt)[64]  = (float(*)[64])SM;
    float (*Ft)[256] = (float(*)[256])(SM + 1024);
    float* bias_p    = SM + 5120;
    float* bias_s    = SM + 5376;

    const int tid = threadIdx.x;
    const float s = -0.00625f;

    const float* mlv_b = mlv + (size_t)b * TXT * 160;
    const float* ms_b  = ms  + (size_t)b * NMELC * MELT;

    {
        const int jj = tid >> 2;
        const int q  = tid & 3;
        const float* p = mlv_b + (size_t)(j0 + jj) * 160 + q * 20;
        float part = 0.f;
        #pragma unroll
        for (int c = 0; c < 20; ++c) {
            float mu = p[c];
            float lv = p[c + 80];
            float iv = __expf(-lv);
            part += mu * mu * iv + lv;
        }
        bias_p[tid] = part;
    }
    __syncthreads();
    if (tid < 64) {
        float v = bias_p[tid * 4] + bias_p[tid * 4 + 1] +
                  bias_p[tid * 4 + 2] + bias_p[tid * 4 + 3];
        bias_s[tid] = s * v;
    }

    float acc[8][8];
    #pragma unroll
    for (int i = 0; i < 8; ++i)
        #pragma unroll
        for (int k = 0; k < 8; ++k) acc[i][k] = 0.f;

    const int jg = tid >> 5;
    const int tg = tid & 31;

    for (int kc = 0; kc < 10; ++kc) {
        const int c0 = kc * 8;
        __syncthreads();
        #pragma unroll
        for (int i = 0; i < 2; ++i) {
            int f   = tid + i * 256;
            int cr  = f >> 6;
            int col = f & 63;
            float mu = mlv_b[(size_t)(j0 + col) * 160 + (c0 + cr)];
            float lv = mlv_b[(size_t)(j0 + col) * 160 + (80 + c0 + cr)];
            float iv = __expf(-lv);
            Gt[cr][col]     = s * iv;
            Gt[cr + 8][col] = -2.f * s * mu * iv;
        }
        #pragma unroll
        for (int i = 0; i < 2; ++i) {
            int f   = tid + i * 256;
            int row = f >> 6;
            int c4  = f & 63;
            int t   = t0 + c4 * 4;
            float4 v = (t + 3 < MELT)
                ? *(const float4*)&ms_b[(size_t)(c0 + row) * MELT + t]
                : make_float4(0.f, 0.f, 0.f, 0.f);
            *(float4*)&Ft[row][c4 * 4] =
                make_float4(v.x * v.x, v.y * v.y, v.z * v.z, v.w * v.w);
            *(float4*)&Ft[row + 8][c4 * 4] = v;
        }
        __syncthreads();
        #pragma unroll
        for (int k = 0; k < 16; ++k) {
            float4 g0 = *(const float4*)&Gt[k][jg * 8];
            float4 g1 = *(const float4*)&Gt[k][jg * 8 + 4];
            float4 f0 = *(const float4*)&Ft[k][tg * 8];
            float4 f1 = *(const float4*)&Ft[k][tg * 8 + 4];
            float ga[8] = {g0.x, g0.y, g0.z, g0.w, g1.x, g1.y, g1.z, g1.w};
            float fa[8] = {f0.x, f0.y, f0.z, f0.w, f1.x, f1.y, f1.z, f1.w};
            #pragma unroll
            for (int ji = 0; ji < 8; ++ji)
                #pragma unroll
                for (int ti = 0; ti < 8; ++ti)
                    acc[ji][ti] = fmaf(ga[ji], fa[ti], acc[ji][ti]);
        }
    }

    #pragma unroll
    for (int ji = 0; ji < 8; ++ji) {
        int j = j0 + jg * 8 + ji;
        float bs = bias_s[jg * 8 + ji];
        float* orow = out_lp + (size_t)(b * TXT + j) * MELT;
        #pragma unroll
        for (int ti = 0; ti < 8; ++ti) {
            int t = t0 + tg * 8 + ti;
            if (t < MELT) orow[t] = acc[ji][ti] + bs;
        }
    }
}

// ---------------------------------------------------------------------------
// dp block body: r9-verified structure. 2 j/lane, systolic skew i=t+l, DPP
// wave_shr:1 neighbor, 3 waves + 2 LDS rings, 3-deep prefetch from out_lp.
// Optional `flags` (16x8 ints): acquire-poll per 256-t chunk (producer =
// 5 lp j-tile blocks release-incrementing). SM: bnd[2][2056] @0, prog @4112.
// ---------------------------------------------------------------------------
__device__ __forceinline__ void dp_block(
    const float* __restrict__ lp, const int* __restrict__ tlen,
    const int* __restrict__ mlen, float* __restrict__ res,
    float* __restrict__ out0, int b, float* SM, int* flags)
{
    float (*bnd)[2056] = (float(*)[2056])SM;
    int* prog = (int*)(SM + 4112);

    const int tid  = threadIdx.x;
    const int w    = tid >> 6;
    const int l    = tid & 63;
    const int tend = mlen[b] - 1;
    const int tl   = tlen[b];

    if (tid < 2) prog[tid] = 0;
    if (l == 63 && w < 2) bnd[w][0] = -PADM;
    __syncthreads();
    if (tid >= 192) return;          // wave 3 idle (after full-block barrier)

#define CHUNK_WAIT(C_)                                                       \
    while (__hip_atomic_load(&flags[(b << 3) + (C_)], __ATOMIC_ACQUIRE,      \
                             __HIP_MEMORY_SCOPE_AGENT) < 5)                  \
        __builtin_amdgcn_s_sleep(8);

    int lastC = 0;
    if (flags) { CHUNK_WAIT(0) }

    int j0c = 2 * tid; if (j0c > 318) j0c = 318;
    const float* r0 = lp + (size_t)(b * TXT + j0c) * MELT;
    const float* r1 = r0 + MELT;

    float A1 = (tid == 0) ? lp[(size_t)b * TXT * MELT] * L2E : -PADM;
    float A2 = -PADM;
    float A1F = A1, A2F = A2;

    if (w == 2 && tl < 257) return;  // wave 2 unused for this batch

    float ptA2 = -PADM, ptB2 = -PADM;
    const bool is0     = (l == 0);
    const bool isPub   = (l == 63) && (w < 2);
    const bool hasRing = (w > 0);
    int seen = 0;

    const int imax = tend + 63;

    float PA[16], PB[16], PC[16];
    #pragma unroll
    for (int q = 0; q < 8; ++q) { PA[2*q] = r0[1 + q - l]; PA[2*q+1] = r1[1 + q - l]; }
    #pragma unroll
    for (int q = 0; q < 8; ++q) { PB[2*q] = r0[9 + q - l]; PB[2*q+1] = r1[9 + q - l]; }
    #pragma unroll
    for (int q = 0; q < 16; ++q) PA[q] = fmaf(PA[q], L2E, EPSL2);

    const float* p0 = r0 + 17 - l;
    const float* p1 = r1 + 17 - l;

#define RING_RD(BQ_, T0_)                                                    \
    {                                                                        \
        float4 q0_ = *(const float4*)&bnd[w - 1][T0_];                       \
        float4 q1_ = *(const float4*)&bnd[w - 1][(T0_) + 4];                 \
        BQ_[0]=q0_.x; BQ_[1]=q0_.y; BQ_[2]=q0_.z; BQ_[3]=q0_.w;              \
        BQ_[4]=q1_.x; BQ_[5]=q1_.y; BQ_[6]=q1_.z; BQ_[7]=q1_.w;              \
    }
#define RING_POLL(NEED_)                                                     \
    if (seen < (NEED_)) {                                                    \
        int tgt_ = (NEED_) + 32;                                             \
        if (tgt_ > tend - 1) tgt_ = tend - 1;                                \
        if (tgt_ < (NEED_)) tgt_ = (NEED_);                                  \
        volatile int* pv_ = &prog[w - 1];                                    \
        int v_ = *pv_;                                                       \
        while (v_ < tgt_) { __builtin_amdgcn_s_sleep(1); v_ = *pv_; }        \
        seen = v_;                                                           \
        __asm__ volatile("" ::: "memory");                                   \
    }
#define CHUNK_STEP(I0_)                                                      \
    if (flags) {                                                             \
        int cN_ = ((I0_) + 31) >> 8; if (cN_ > 7) cN_ = 7;                   \
        while (lastC < cN_) { ++lastC; CHUNK_WAIT(lastC) }                   \
    }

    float bqC[8];
    if (hasRing) {
        RING_POLL(7)
        RING_RD(bqC, 0)
    } else {
        #pragma unroll
        for (int q = 0; q < 8; ++q) bqC[q] = -PADM;
    }

#define STEP2(Pc_, q_, AQ_)                                                  \
    {                                                                        \
        float pt_ = is0 ? bqC[q_] : ptA2;                                    \
        float m1_ = fmaxf(A1, pt_);                                          \
        float d1_ = A1 - pt_;                                                \
        float e1_ = __builtin_amdgcn_exp2f(-fabsf(d1_));                     \
        float g1_ = __builtin_amdgcn_logf(1.0f + e1_);                       \
        float n1_ = m1_ + g1_ + Pc_[2 * q_];                                 \
        float m2_ = fmaxf(A2, A1);                                           \
        float d2_ = A2 - A1;                                                 \
        float e2_ = __builtin_amdgcn_exp2f(-fabsf(d2_));                     \
        float g2_ = __builtin_amdgcn_logf(1.0f + e2_);                       \
        float n2_ = m2_ + g2_ + Pc_[2 * q_ + 1];                             \
        float ns_ = __int_as_float(__builtin_amdgcn_update_dpp(              \
            0, __float_as_int(n2_), 0x138, 0xF, 0xF, false));                \
        ptA2 = ptB2; ptB2 = ns_;                                             \
        A1 = n1_; A2 = n2_; AQ_ = n2_;                                       \
    }

#define GROUP2_S(Pc_, Pm_, Pl_, I0_)                                         \
{                                                                            \
    CHUNK_STEP(I0_)                                                          \
    float bqN[8];                                                            \
    if (hasRing) {                                                           \
        const int nt0_ = (I0_) + 7;                                          \
        RING_POLL(nt0_ + 7)                                                  \
        RING_RD(bqN, nt0_)                                                   \
    } else {                                                                 \
        _Pragma("unroll") for (int q_=0;q_<8;++q_) bqN[q_] = -PADM;          \
    }                                                                        \
    _Pragma("unroll") for (int q_=0;q_<8;++q_) {                             \
        Pl_[2*q_] = p0[q_]; Pl_[2*q_+1] = p1[q_];                            \
    }                                                                        \
    float aq2[8];                                                            \
    _Pragma("unroll")                                                        \
    for (int q_=0;q_<8;++q_) STEP2(Pc_, q_, aq2[q_])                         \
    if (isPub) {                                                             \
        const int t63_ = (I0_) - 63;                                         \
        if (t63_ >= 1) {                                                     \
            _Pragma("unroll") for (int q_=0;q_<8;++q_)                       \
                bnd[w][t63_ + q_] = aq2[q_];                                 \
        } else {                                                             \
            _Pragma("unroll") for (int q_=0;q_<8;++q_)                       \
                if (t63_ + q_ >= 1) bnd[w][t63_ + q_] = aq2[q_];             \
        }                                                                    \
        __asm__ volatile("" ::: "memory");                                   \
        int pgv_ = t63_ + 7;                                                 \
        if (pgv_ >= 1) prog[w] = pgv_;                                       \
    }                                                                        \
    p0 += 8; p1 += 8;                                                        \
    _Pragma("unroll") for (int q_=0;q_<16;++q_)                              \
        Pm_[q_] = fmaf(Pm_[q_], L2E, EPSL2);                                 \
    _Pragma("unroll") for (int q_=0;q_<8;++q_) bqC[q_] = bqN[q_];            \
}

#define GROUP2_T(Pc_, Pm_, Pl_, I0_)                                         \
{                                                                            \
    CHUNK_STEP(I0_)                                                          \
    float bqN[8];                                                            \
    if (hasRing) {                                                           \
        const int nt0_ = (I0_) + 7;                                          \
        int need_ = nt0_ + 7; if (need_ > tend - 1) need_ = tend - 1;        \
        RING_POLL(need_)                                                     \
        const int rb_ = nt0_ > 2048 ? 2048 : nt0_;                           \
        RING_RD(bqN, rb_)                                                    \
    } else {                                                                 \
        _Pragma("unroll") for (int q_=0;q_<8;++q_) bqN[q_] = -PADM;          \
    }                                                                        \
    _Pragma("unroll") for (int q_=0;q_<8;++q_) {                             \
        int t_ = (I0_) + 16 + q_ - l;                                        \
        t_ = t_ < 0 ? 0 : (t_ > tend ? tend : t_);                           \
        Pl_[2*q_] = r0[t_]; Pl_[2*q_+1] = r1[t_];                            \
    }                                                                        \
    float aq2[8];                                                            \
    const int vt_ = (I0_) - l;                                               \
    _Pragma("unroll")                                                        \
    for (int q_=0;q_<8;++q_) {                                               \
        STEP2(Pc_, q_, aq2[q_])                                              \
        bool c_ = (vt_ + q_ == tend);                                        \
        A1F = c_ ? A1 : A1F;                                                 \
        A2F = c_ ? A2 : A2F;                                                 \
    }                                                                        \
    if (isPub) {                                                             \
        const int t63_ = (I0_) - 63;                                         \
        _Pragma("unroll") for (int q_=0;q_<8;++q_) {                         \
            int tq_ = t63_ + q_;                                             \
            if (tq_ >= 1 && tq_ <= tend) bnd[w][tq_] = aq2[q_];              \
        }                                                                    \
        __asm__ volatile("" ::: "memory");                                   \
        int pgv_ = t63_ + 7; if (pgv_ > tend) pgv_ = tend;                   \
        if (pgv_ >= 1) prog[w] = pgv_;                                       \
    }                                                                        \
    _Pragma("unroll") for (int q_=0;q_<16;++q_)                              \
        Pm_[q_] = fmaf(Pm_[q_], L2E, EPSL2);                                 \
    _Pragma("unroll") for (int q_=0;q_<8;++q_) bqC[q_] = bqN[q_];            \
}

    int i0 = 1;
    const int sEnd = tend - 23;
    int ph = 0;
    while (i0 <= sEnd) {
        GROUP2_S(PA, PB, PC, i0); i0 += 8;
        if (i0 > sEnd) { ph = 1; break; }
        GROUP2_S(PB, PC, PA, i0); i0 += 8;
        if (i0 > sEnd) { ph = 2; break; }
        GROUP2_S(PC, PA, PB, i0); i0 += 8;
    }
    if (ph == 1) {
        #pragma unroll
        for (int q = 0; q < 16; ++q) {
            float tmp = PA[q]; PA[q] = PB[q]; PB[q] = PC[q]; PC[q] = tmp;
        }
    } else if (ph == 2) {
        #pragma unroll
        for (int q = 0; q < 16; ++q) {
            float tmp = PA[q]; PA[q] = PC[q]; PC[q] = PB[q]; PB[q] = tmp;
        }
    }
    while (i0 <= imax) {
        GROUP2_T(PA, PB, PC, i0); i0 += 8;
        if (i0 > imax) break;
        GROUP2_T(PB, PC, PA, i0); i0 += 8;
        if (i0 > imax) break;
        GROUP2_T(PC, PA, PB, i0); i0 += 8;
    }

#undef GROUP2_S
#undef GROUP2_T
#undef STEP2
#undef RING_RD
#undef RING_POLL
#undef CHUNK_STEP
#undef CHUNK_WAIT

    if (tid == ((tl - 1) >> 1)) {
        float Af = ((tl - 1) & 1) ? A2F : A1F;
        float v = Af * LN2 / (float)(tend + 1);
        if (res) res[b] = v;
        else     atomicAdd(out0, -v / (float)BATCH);
    }
}

// ---------------------------------------------------------------------------
// Fused kernel: blocks 0..15 = dp (consumer), 16..2575 = lp (producer).
// lp block order: t-chunk OUTERMOST (chunk c done early for all batches).
// Signal: per-(b, t-chunk) counter, release-add by each of 5 j-tile blocks.
// ---------------------------------------------------------------------------
__global__ __launch_bounds__(256) void fused_kernel(
    const float* __restrict__ mlv, const float* __restrict__ ms,
    float* __restrict__ out_lp,
    const int* __restrict__ tlen, const int* __restrict__ mlen,
    float* __restrict__ res, int* __restrict__ flags)
{
    __shared__ float SM[5440];
    const int blk = blockIdx.x;
    if (blk < BATCH) {
        dp_block(out_lp, tlen, mlen, res, nullptr, blk, SM, flags);
        return;
    }
    const int r  = blk - BATCH;
    const int tc = r / 80;          // t-chunk 0..7 (outermost)
    const int rem = r % 80;
    const int b  = rem / 5;
    const int jt = rem % 5;
    lp_block(mlv, ms, out_lp, b, jt * 64, tc * 256, SM);
    __syncthreads();
    if (threadIdx.x == 0)
        __hip_atomic_fetch_add(&flags[(b << 3) + tc], 1,
                               __ATOMIC_RELEASE, __HIP_MEMORY_SCOPE_AGENT);
}

// ---------------------------------------------------------------------------
// Standalone fallbacks (sequential path when ws too small for flags).
// ---------------------------------------------------------------------------
__global__ __launch_bounds__(256) void lp_kernel(
    const float* __restrict__ mlv, const float* __restrict__ ms,
    float* __restrict__ out_lp)
{
    __shared__ float SM[5440];
    lp_block(mlv, ms, out_lp, blockIdx.z, blockIdx.y * 64, blockIdx.x * 256, SM);
}

__global__ __launch_bounds__(256) void dp_kernel_fb(
    const float* __restrict__ lp, const int* __restrict__ tlen,
    const int* __restrict__ mlen, float* __restrict__ res,
    float* __restrict__ out0)
{
    __shared__ float SM[5440];
    dp_block(lp, tlen, mlen, res, out0, blockIdx.x, SM, nullptr);
}

__global__ void init_kernel(int* flags, float* out0, int zero_out)
{
    if (threadIdx.x < 128) flags[threadIdx.x] = 0;
    if (threadIdx.x == 0 && zero_out) out0[0] = 0.f;
}

__global__ void fin_kernel(const float* __restrict__ res, float* __restrict__ out0)
{
    int l = threadIdx.x;
    float v = (l < BATCH) ? res[l] : 0.f;
    #pragma unroll
    for (int off = 32; off; off >>= 1) v += __shfl_down(v, off);
    if (l == 0) out0[0] = -(v / (float)BATCH);
}

// ---------------------------------------------------------------------------
extern "C" void kernel_launch(void* const* d_in, const int* in_sizes, int n_in,
                              void* d_out, int out_size, void* d_ws, size_t ws_size,
                              hipStream_t stream)
{
    const float* mlv = (const float*)d_in[0];
    const float* ms  = (const float*)d_in[1];
    const int*   tl  = (const int*)d_in[2];
    const int*   ml  = (const int*)d_in[3];
    float* out    = (float*)d_out;
    float* out_lp = out + 1;

    bool res_ok   = ws_size >= 64;
    bool fused_ok = ws_size >= 64 + 512;
    float* res  = res_ok ? (float*)d_ws : nullptr;
    int*  flags = fused_ok ? (int*)((char*)d_ws + 64) : nullptr;

    if (fused_ok) {
        init_kernel<<<1, 128, 0, stream>>>(flags, out, 0);
        fused_kernel<<<BATCH + 8 * 5 * BATCH, 256, 0, stream>>>(
            mlv, ms, out_lp, tl, ml, res, flags);
        fin_kernel<<<1, 64, 0, stream>>>(res, out);
    } else {
        dim3 gA(8, 5, 16);
        lp_kernel<<<gA, 256, 0, stream>>>(mlv, ms, out_lp);
        if (!res_ok) init_kernel<<<1, 1, 0, stream>>>((int*)d_ws, out, 1);
        dp_kernel_fb<<<BATCH, 256, 0, stream>>>(out_lp, tl, ml, res, out);
        if (res_ok) fin_kernel<<<1, 64, 0, stream>>>(res, out);
    }
}